// Round 12
// baseline (336.144 us; speedup 1.0000x reference)
//
#include <hip/hip_runtime.h>
#include <cstdint>
#include <cstddef>

// ---------------- constants ----------------
constexpr int B_   = 4096;
constexpr int DIN  = 256;
constexpr int OUT_ = 32;
constexpr int MM   = 128;
constexpr int NH_  = 2;
constexpr int HO   = 64;          // NH*OUT
constexpr int TRIL = 8256;        // 128*129/2
constexpr float JIT = 1e-4f;

// ---------------- workspace layout ----------------
constexpr size_t al4k(size_t x){ return (x + 4095) & ~size_t(4095); }
constexpr size_t OFF_FLAG  = 0;                               // int
constexpr size_t OFF_INVLS = 4096;                            // f32 [2][256]
constexpr size_t OFF_SF2   = al4k(OFF_INVLS + 2*256*4);       // f32 [2]
constexpr size_t OFF_ZN2   = al4k(OFF_SF2 + 64);              // f32 [2][4096]
constexpr size_t OFF_XN2   = al4k(OFF_ZN2 + 8192*4);          // f32 [2][4096]
constexpr size_t OFF_W     = al4k(OFF_XN2 + 8192*4);          // f32 [64][128]
constexpr size_t OFF_ZS    = al4k(OFF_W + 8192*4);            // bf16 [2][4096][256]
constexpr size_t OFF_XS    = al4k(OFF_ZS + (size_t)2097152*2);
constexpr size_t OFF_VTH   = al4k(OFF_XS + (size_t)2097152*2); // bf16 [64][128][128] V^T hi
constexpr size_t OFF_VTL   = al4k(OFF_VTH + (size_t)1048576*2);// bf16 [64][128][128] V^T lo
constexpr size_t OFF_CHI   = al4k(OFF_VTL + (size_t)1048576*2);// bf16 [64][128][128]
constexpr size_t OFF_CLO   = al4k(OFF_CHI + (size_t)1048576*2);

typedef float f32x4 __attribute__((ext_vector_type(4)));
typedef short short8 __attribute__((ext_vector_type(8)));

__device__ __forceinline__ float bf2f(unsigned short u){
  union{unsigned int i; float f;} v; v.i = ((unsigned)u) << 16; return v.f;
}
__device__ __forceinline__ unsigned short f2bf(float f){
  union{float f; unsigned int i;} v; v.f = f;
  unsigned int r = v.i + 0x7fffu + ((v.i >> 16) & 1u);
  return (unsigned short)(r >> 16);
}
__device__ __forceinline__ float ldin(const void* p, size_t i, int isbf){
  if (isbf) return bf2f(((const unsigned short*)p)[i]);
  return ((const float*)p)[i];
}
__device__ __forceinline__ void stout(void* p, size_t i, float v, int isbf){
  if (isbf) ((unsigned short*)p)[i] = f2bf(v);
  else ((float*)p)[i] = v;
}
// async global->LDS, 16B per lane; LDS dest = wave-uniform base + lane*16
__device__ __forceinline__ void gl_lds16(const unsigned short* g, unsigned short* l){
  __builtin_amdgcn_global_load_lds(
      (const __attribute__((address_space(1))) unsigned int*)g,
      (__attribute__((address_space(3))) unsigned int*)l, 16, 0, 0);
}

// ---------------- K1: detect dtype + hypers (merged) ----------------
__global__ void k_hypers(const void* __restrict__ theta, const void* __restrict__ x,
                         int* __restrict__ flagp,
                         float* __restrict__ inv_ls, float* __restrict__ sf2){
  __shared__ int sflag;
  int t = threadIdx.x;
  if (t < 64){
    unsigned int w0 = ((const unsigned int*)theta)[t];
    unsigned int w1 = ((const unsigned int*)x)[t];
    float a0 = fabsf(bf2f((unsigned short)(w0 & 0xffffu)));
    float a1 = fabsf(bf2f((unsigned short)(w1 & 0xffffu)));
    int c = ((a0 > 9.3e-10f && a0 < 64.f) ? 1 : 0) + ((a1 > 9.3e-10f && a1 < 64.f) ? 1 : 0);
    c += __shfl_down(c, 32); c += __shfl_down(c, 16); c += __shfl_down(c, 8);
    c += __shfl_down(c, 4);  c += __shfl_down(c, 2);  c += __shfl_down(c, 1);
    if (t == 0){ sflag = (c >= 64) ? 1 : 0; *flagp = sflag; }
  }
  __syncthreads();
  const int isbf = sflag;
  for (int i = t; i < NH_*257; i += blockDim.x){
    int h = i / 257, j = i - h*257;
    float v = ldin(theta, i, isbf);
    if (j == 0) sf2[h] = __expf(v);
    else inv_ls[h*DIN + j - 1] = __expf(-v);
  }
}

// ---------------- K2: scale x and z by 1/ls -> bf16 + squared norms (merged) --------
__global__ void k_scale(const void* __restrict__ xsrc, const void* __restrict__ zsrc,
                        const int* flagp, const float* __restrict__ inv_ls,
                        unsigned short* __restrict__ xdst, unsigned short* __restrict__ zdst,
                        float* __restrict__ xn2, float* __restrict__ zn2){
  const int isbf = *flagp;
  const int h = blockIdx.y;
  const int wave = threadIdx.x >> 6, lane = threadIdx.x & 63;
  int bx = blockIdx.x;
  const void* src; unsigned short* dst; float* n2; int r;
  if (bx < 1024){ src = xsrc; dst = xdst; n2 = xn2; r = bx*4 + wave; }
  else          { src = zsrc; dst = zdst; n2 = zn2; r = (bx-1024)*4 + wave; }
  const int d0 = lane*4;
  float v[4];
  if (isbf){
    uint2 uu = *(const uint2*)((const unsigned short*)src + (size_t)r*DIN + d0);
    v[0]=bf2f((unsigned short)(uu.x & 0xffffu)); v[1]=bf2f((unsigned short)(uu.x >> 16));
    v[2]=bf2f((unsigned short)(uu.y & 0xffffu)); v[3]=bf2f((unsigned short)(uu.y >> 16));
  } else {
    f32x4 f = *(const f32x4*)((const float*)src + (size_t)r*DIN + d0);
    v[0]=f[0]; v[1]=f[1]; v[2]=f[2]; v[3]=f[3];
  }
  const float* il = inv_ls + h*DIN + d0;
  unsigned short rb[4];
  float p = 0.f;
  #pragma unroll
  for (int k = 0; k < 4; ++k){
    float s = v[k] * il[k];
    rb[k] = f2bf(s);
    float q = bf2f(rb[k]);
    p += q*q;
  }
  uint2 pk;
  pk.x = (unsigned)rb[0] | ((unsigned)rb[1] << 16);
  pk.y = (unsigned)rb[2] | ((unsigned)rb[3] << 16);
  *(uint2*)(dst + ((size_t)h*4096 + r)*DIN + d0) = pk;
  p += __shfl_xor(p, 32); p += __shfl_xor(p, 16); p += __shfl_xor(p, 8);
  p += __shfl_xor(p, 4);  p += __shfl_xor(p, 2);  p += __shfl_xor(p, 1);
  if (lane == 0) n2[(size_t)h*4096 + r] = p;
}

// ---------------- K3: kuu (MFMA) + blocked Cholesky + trtri, fused per head ---------
constexpr int TLD = 20;          // tile leading dim (floats)
constexpr int TSZ = 16*TLD;      // 320 floats per tile
__device__ __forceinline__ int tb(int bi, int bj){ return (bi*(bi+1)/2 + bj)*TSZ; }
__device__ __forceinline__ int vb(int bi, int bj){ return (36 + bi*(bi-1)/2 + bj)*TSZ; }
__device__ __forceinline__ int tri_bi(int t){
  int bi = (int)((sqrtf(8.f*t + 1.f) - 1.f) * 0.5f);
  while ((bi+1)*(bi+2)/2 <= t) ++bi;
  while (bi*(bi+1)/2 > t) --bi;
  return bi;
}

__global__ __launch_bounds__(256) void k_kufact(
    const unsigned short* __restrict__ zs, const float* __restrict__ zn2,
    const float* __restrict__ sf2,
    unsigned short* __restrict__ VTh, unsigned short* __restrict__ VTl){
  const int ho = blockIdx.x, h = ho >> 5;
  const int tid = threadIdx.x;
  const int lane = tid & 63, wid = tid >> 6;
  const int l15 = lane & 15, q = lane >> 4;
  const int wn = wid * 32;
  extern __shared__ float T[];      // 64 tiles (80 KB); staging zsl aliases T[0..2048)
  unsigned short* zsl = (unsigned short*)T;   // [128][32] swizzled
  float* zn2l = T + 64*TSZ;                   // [128]
  if (tid < 128) zn2l[tid] = zn2[ho*128 + tid];
  const size_t zbase = (size_t)ho * 32768;
  const int sw = ((q ^ ((l15 >> 1) & 3)) << 3);
  const f32x4 z4 = {0.f,0.f,0.f,0.f};
  f32x4 acc[8][2];
  #pragma unroll
  for (int mt=0; mt<8; ++mt){ acc[mt][0]=z4; acc[mt][1]=z4; }
  for (int kc = 0; kc < 8; ++kc){
    __syncthreads();
    {
      int rA = wn + (lane >> 2);
      int sg = ((lane & 3) ^ ((rA >> 1) & 3)) << 3;
      gl_lds16(zs + zbase + (size_t)rA*256 + kc*32 + sg, zsl + wn*32);
      gl_lds16(zs + zbase + (size_t)(rA+16)*256 + kc*32 + sg, zsl + (wn+16)*32);
    }
    __syncthreads();
    short8 b0 = *(const short8*)(zsl + (wn      + l15)*32 + sw);
    short8 b1 = *(const short8*)(zsl + (wn + 16 + l15)*32 + sw);
    #pragma unroll
    for (int mt=0; mt<8; ++mt){
      short8 a = *(const short8*)(zsl + (mt*16 + l15)*32 + sw);
      acc[mt][0] = __builtin_amdgcn_mfma_f32_16x16x32_bf16(a, b0, acc[mt][0], 0,0,0);
      acc[mt][1] = __builtin_amdgcn_mfma_f32_16x16x32_bf16(a, b1, acc[mt][1], 0,0,0);
    }
  }
  __syncthreads();   // all zsl reads done before tiles (alias) are written
  // ---- epilogue: kuu -> T tiles (lower + full diag), + jitter ----
  const float s2v = sf2[h];
  #pragma unroll
  for (int nt=0; nt<2; ++nt){
    int n = wn + nt*16 + l15;
    float nn = zn2l[n];
    int bn = n >> 4;
    #pragma unroll
    for (int mt=0; mt<8; ++mt){
      #pragma unroll
      for (int r=0; r<4; ++r){
        int m = mt*16 + q*4 + r;
        float d2 = fmaxf(zn2l[m] + nn - 2.f*acc[mt][nt][r], 0.f);
        float a = s2v * __expf(-0.5f*d2);
        if (m == n) a += JIT;
        int bm = m >> 4;
        if (bn <= bm) T[tb(bm, bn) + (m & 15)*TLD + (n & 15)] = a;
      }
    }
  }
  __syncthreads();
  // ---- blocked Cholesky, panel width 16 ----
  for (int kb = 0; kb < 8; ++kb){
    if (wid == 0){
      float* D = T + tb(kb, kb);
      const int r = lane & 15;
      const bool act = (lane < 16);
      float a[16];
      #pragma unroll
      for (int k = 0; k < 16; ++k) a[k] = 0.f;
      if (act){
        #pragma unroll
        for (int k2 = 0; k2 < 4; ++k2)
          *(f32x4*)(a + 4*k2) = *(const f32x4*)(D + r*TLD + 4*k2);
      }
      #pragma unroll
      for (int c = 0; c < 16; ++c){
        float pr[16];
        #pragma unroll
        for (int k = 0; k < 16; ++k) pr[k] = __shfl(a[k], c);
        float rsq = rsqrtf(pr[c]);
        if (act && r >= c) a[c] *= rsq;
        float lrc = a[c];
        #pragma unroll
        for (int k = 0; k < 16; ++k)
          if (k > c && act && r > c) a[k] -= lrc * (pr[k] * rsq);
      }
      float v[16];
      #pragma unroll
      for (int k = 0; k < 16; ++k) v[k] = 0.f;
      const int c = lane & 15;
      #pragma unroll
      for (int i = 0; i < 16; ++i){
        float lrow[16];
        #pragma unroll
        for (int k = 0; k < 16; ++k) lrow[k] = __shfl(a[k], i);
        float rli = 1.f / lrow[i];
        float s = 0.f;
        #pragma unroll
        for (int k = 0; k < 16; ++k)
          if (k < i) s += ((k >= c) ? lrow[k]*v[k] : 0.f);
        v[i] = (c == i) ? rli : ((c < i) ? -s*rli : 0.f);
      }
      if (act){
        #pragma unroll
        for (int i = 0; i < 16; ++i) D[i*TLD + c] = v[i];
      }
    }
    __syncthreads();
    {
      const int gi = kb*16 + 16 + tid;
      if (gi < 128){
        float* Bp = T + tb(gi >> 4, kb) + (gi & 15)*TLD;
        const float* Vd = T + tb(kb, kb);
        float b[16], nb[16];
        #pragma unroll
        for (int k2 = 0; k2 < 4; ++k2) *(f32x4*)(b + 4*k2) = *(const f32x4*)(Bp + 4*k2);
        #pragma unroll
        for (int j = 0; j < 16; ++j){
          float s = 0.f;
          #pragma unroll
          for (int k = 0; k < 16; ++k)
            if (k <= j) s += b[k] * Vd[j*TLD + k];
          nb[j] = s;
        }
        #pragma unroll
        for (int k2 = 0; k2 < 4; ++k2) *(f32x4*)(Bp + 4*k2) = *(const f32x4*)(nb + 4*k2);
      }
    }
    __syncthreads();
    {
      const int D8 = 7 - kb;
      const int Tn = D8*(D8+1)/2;
      const int r15 = lane & 15, cg = lane >> 4, c0 = cg*4;
      for (int tt = wid; tt < Tn; tt += 4){
        int bi1 = tri_bi(tt);
        int bj1 = tt - bi1*(bi1+1)/2;
        int bi = kb + 1 + bi1, bj = kb + 1 + bj1;
        const float* Lr = T + tb(bi, kb) + r15*TLD;
        const float* Lc = T + tb(bj, kb) + c0*TLD;
        float* Cp = T + tb(bi, bj) + r15*TLD + c0;
        float lr[16];
        #pragma unroll
        for (int k2 = 0; k2 < 4; ++k2) *(f32x4*)(lr + 4*k2) = *(const f32x4*)(Lr + 4*k2);
        f32x4 accv = *(const f32x4*)Cp;
        #pragma unroll
        for (int cc = 0; cc < 4; ++cc){
          float lc[16];
          #pragma unroll
          for (int k2 = 0; k2 < 4; ++k2) *(f32x4*)(lc + 4*k2) = *(const f32x4*)(Lc + cc*TLD + 4*k2);
          float s = 0.f;
          #pragma unroll
          for (int k = 0; k < 16; ++k) s += lr[k]*lc[k];
          accv[cc] -= s;
        }
        *(f32x4*)Cp = accv;
      }
    }
    __syncthreads();
  }
  // ---- trtri by anti-diagonal wavefronts ----
  {
    const int r15 = lane & 15, c0 = (lane >> 4)*4;
    for (int d = 1; d < 8; ++d){
      for (int tt = wid; tt < 8 - d; tt += 4){
        const int bi = d + tt, jb = bi - d;
        float W0=0.f, W1=0.f, W2=0.f, W3=0.f;
        for (int k = jb; k < bi; ++k){
          const float* Lt = T + tb(bi, k) + r15*TLD;
          const float* Vt = (k == jb) ? (T + tb(jb, jb)) : (T + vb(k, jb));
          float lr[16];
          #pragma unroll
          for (int k2 = 0; k2 < 4; ++k2) *(f32x4*)(lr + 4*k2) = *(const f32x4*)(Lt + 4*k2);
          #pragma unroll
          for (int kk = 0; kk < 16; ++kk){
            f32x4 vv = *(const f32x4*)(Vt + kk*TLD + c0);
            W0 += lr[kk]*vv[0]; W1 += lr[kk]*vv[1];
            W2 += lr[kk]*vv[2]; W3 += lr[kk]*vv[3];
          }
        }
        const float* Vd = T + tb(bi, bi) + r15*TLD;
        const int cgl = (lane >> 4);
        f32x4 Rr = {0.f,0.f,0.f,0.f};
        #pragma unroll
        for (int k = 0; k < 16; ++k){
          float vd = Vd[k];
          float w0 = __shfl(W0, (cgl<<4)|k);
          float w1 = __shfl(W1, (cgl<<4)|k);
          float w2 = __shfl(W2, (cgl<<4)|k);
          float w3 = __shfl(W3, (cgl<<4)|k);
          Rr[0] -= vd*w0; Rr[1] -= vd*w1; Rr[2] -= vd*w2; Rr[3] -= vd*w3;
        }
        *(f32x4*)(T + vb(bi, jb) + r15*TLD + c0) = Rr;
      }
      __syncthreads();
    }
  }
  // ---- epilogue: VT dense bf16 hi/lo (VT[c][r] = V[r][c]) ----
  const size_t obase = (size_t)ho * 16384;
  for (int e = tid; e < 16384; e += 256){
    int c = e >> 7, rr = e & 127;
    int bc = c >> 4, br = rr >> 4;
    float v = 0.f;
    if (br == bc)      v = T[tb(br, bc) + (rr & 15)*TLD + (c & 15)];
    else if (br > bc)  v = T[vb(br, bc) + (rr & 15)*TLD + (c & 15)];
    unsigned short hi = f2bf(v);
    unsigned short lo = f2bf(v - bf2f(hi));
    VTh[obase + e] = hi;
    VTl[obase + e] = lo;
  }
}

// ---------------- K4: fused Q = V^T V + w + P = Q S + C = Q - P P^T (all MFMA) ------
__global__ __launch_bounds__(256) void k_QPC(
    const unsigned short* __restrict__ VTh, const unsigned short* __restrict__ VTl,
    const void* __restrict__ u_mean, const void* __restrict__ u_tril, const int* flagp,
    float* __restrict__ wg, unsigned short* __restrict__ Chi,
    unsigned short* __restrict__ Clo){
  const int ho = blockIdx.x, o = ho & 31;
  const int tid = threadIdx.x;
  const int lane = tid & 63, l15 = lane & 15, q = lane >> 4;
  const int wn = (tid >> 6) * 32;
  const int wave = tid >> 6;
  const int isbf = *flagp;
  extern __shared__ char smem[];
  unsigned short* Qh  = (unsigned short*)smem;              // [128][136], aliases staging
  unsigned short* Ql  = (unsigned short*)(smem + 34816);    // [128][136]
  unsigned short* Sth = (unsigned short*)(smem + 69632);    // [128][136]
  unsigned short* Stl = (unsigned short*)(smem + 104448);   // [128][136]
  float* ul    = (float*)(smem + 139264);                   // [128]
  float* wpart = ul + 128;                                  // [4][128]
  unsigned short* hsl = Qh;             // staging alias [128][32]
  unsigned short* lsl = Qh + 4096;
  if (tid < 128) ul[tid] = ldin(u_mean, (size_t)o*128 + tid, isbf);
  // ---- fill St = S^T (row j holds S[:,j]) as bf16 hi/lo ----
  for (int e = tid; e < 16384; e += 256){
    int j = e >> 7, k = e & 127;
    float val = 0.f;
    if (k >= j) val = ldin(u_tril, (size_t)o*TRIL + (size_t)k*(k+1)/2 + j, isbf);
    unsigned short hi = f2bf(val);
    Sth[j*136 + k] = hi;
    Stl[j*136 + k] = f2bf(val - bf2f(hi));
  }
  const size_t vbase = (size_t)ho * 16384;
  const int sw = ((q ^ ((l15 >> 1) & 3)) << 3);
  const f32x4 z4 = {0.f,0.f,0.f,0.f};
  // ---- phase Q: Q = VT * VT^T via hi/lo 3-pass MFMA ----
  f32x4 acc[8][2];
  #pragma unroll
  for (int mt=0; mt<8; ++mt){ acc[mt][0]=z4; acc[mt][1]=z4; }
  for (int kc = 0; kc < 4; ++kc){
    __syncthreads();
    {
      int rA = wn + (lane >> 2);
      int sg = ((lane & 3) ^ ((rA >> 1) & 3)) << 3;
      gl_lds16(VTh + vbase + (size_t)rA*128 + kc*32 + sg, hsl + wn*32);
      gl_lds16(VTl + vbase + (size_t)rA*128 + kc*32 + sg, lsl + wn*32);
      gl_lds16(VTh + vbase + (size_t)(rA+16)*128 + kc*32 + sg, hsl + (wn+16)*32);
      gl_lds16(VTl + vbase + (size_t)(rA+16)*128 + kc*32 + sg, lsl + (wn+16)*32);
    }
    __syncthreads();
    short8 b0h = *(const short8*)(hsl + (wn      + l15)*32 + sw);
    short8 b1h = *(const short8*)(hsl + (wn + 16 + l15)*32 + sw);
    short8 b0l = *(const short8*)(lsl + (wn      + l15)*32 + sw);
    short8 b1l = *(const short8*)(lsl + (wn + 16 + l15)*32 + sw);
    #pragma unroll
    for (int mt=0; mt<8; ++mt){
      short8 ah = *(const short8*)(hsl + (mt*16 + l15)*32 + sw);
      short8 al = *(const short8*)(lsl + (mt*16 + l15)*32 + sw);
      acc[mt][0] = __builtin_amdgcn_mfma_f32_16x16x32_bf16(ah, b0h, acc[mt][0], 0,0,0);
      acc[mt][0] = __builtin_amdgcn_mfma_f32_16x16x32_bf16(ah, b0l, acc[mt][0], 0,0,0);
      acc[mt][0] = __builtin_amdgcn_mfma_f32_16x16x32_bf16(al, b0h, acc[mt][0], 0,0,0);
      acc[mt][1] = __builtin_amdgcn_mfma_f32_16x16x32_bf16(ah, b1h, acc[mt][1], 0,0,0);
      acc[mt][1] = __builtin_amdgcn_mfma_f32_16x16x32_bf16(ah, b1l, acc[mt][1], 0,0,0);
      acc[mt][1] = __builtin_amdgcn_mfma_f32_16x16x32_bf16(al, b1h, acc[mt][1], 0,0,0);
    }
  }
  // ---- w = Q u (shuffle reduce) ----
  {
    float u0 = ul[wn + l15], u1 = ul[wn + 16 + l15];
    float wpm[32];
    #pragma unroll
    for (int mt=0; mt<8; ++mt){
      #pragma unroll
      for (int r=0; r<4; ++r)
        wpm[mt*4+r] = acc[mt][0][r]*u0 + acc[mt][1][r]*u1;
    }
    #pragma unroll
    for (int i = 0; i < 32; ++i){
      wpm[i] += __shfl_xor(wpm[i], 1);
      wpm[i] += __shfl_xor(wpm[i], 2);
      wpm[i] += __shfl_xor(wpm[i], 4);
      wpm[i] += __shfl_xor(wpm[i], 8);
    }
    if (l15 == 0){
      #pragma unroll
      for (int i = 0; i < 32; ++i){
        int m = (i>>2)*16 + q*4 + (i&3);
        wpart[wave*128 + m] = wpm[i];
      }
    }
  }
  __syncthreads();   // staging reads done (safe to overwrite Qh region) + wpart visible
  if (tid < 128)
    wg[ho*128 + tid] = wpart[tid] + wpart[128+tid] + wpart[256+tid] + wpart[384+tid];
  // ---- write Q dense bf16 hi/lo to LDS ----
  {
    const int n0 = wn + l15, n1 = wn + 16 + l15;
    #pragma unroll
    for (int mt=0; mt<8; ++mt){
      #pragma unroll
      for (int r=0; r<4; ++r){
        int m = mt*16 + q*4 + r;
        float v0 = acc[mt][0][r], v1 = acc[mt][1][r];
        unsigned short h0 = f2bf(v0), h1 = f2bf(v1);
        Qh[m*136 + n0] = h0; Ql[m*136 + n0] = f2bf(v0 - bf2f(h0));
        Qh[m*136 + n1] = h1; Ql[m*136 + n1] = f2bf(v1 - bf2f(h1));
      }
    }
  }
  __syncthreads();   // Qh/Ql + Sth/Stl visible
  // ---- phase P: P = Q*S via MFMA, 3 passes ----
  f32x4 acc3[8][2];
  #pragma unroll
  for (int mt=0; mt<8; ++mt){ acc3[mt][0]=z4; acc3[mt][1]=z4; }
  #pragma unroll
  for (int kc2 = 0; kc2 < 4; ++kc2){
    const int ko = kc2*32 + q*8;
    short8 b0h = *(const short8*)(Sth + (wn      + l15)*136 + ko);
    short8 b1h = *(const short8*)(Sth + (wn + 16 + l15)*136 + ko);
    short8 b0l = *(const short8*)(Stl + (wn      + l15)*136 + ko);
    short8 b1l = *(const short8*)(Stl + (wn + 16 + l15)*136 + ko);
    #pragma unroll
    for (int mt=0; mt<8; ++mt){
      short8 ah = *(const short8*)(Qh + (mt*16 + l15)*136 + ko);
      short8 al = *(const short8*)(Ql + (mt*16 + l15)*136 + ko);
      acc3[mt][0] = __builtin_amdgcn_mfma_f32_16x16x32_bf16(ah, b0h, acc3[mt][0], 0,0,0);
      acc3[mt][0] = __builtin_amdgcn_mfma_f32_16x16x32_bf16(al, b0h, acc3[mt][0], 0,0,0);
      acc3[mt][0] = __builtin_amdgcn_mfma_f32_16x16x32_bf16(ah, b0l, acc3[mt][0], 0,0,0);
      acc3[mt][1] = __builtin_amdgcn_mfma_f32_16x16x32_bf16(ah, b1h, acc3[mt][1], 0,0,0);
      acc3[mt][1] = __builtin_amdgcn_mfma_f32_16x16x32_bf16(al, b1h, acc3[mt][1], 0,0,0);
      acc3[mt][1] = __builtin_amdgcn_mfma_f32_16x16x32_bf16(ah, b1l, acc3[mt][1], 0,0,0);
    }
  }
  __syncthreads();   // all Qh/Ql reads done before overwrite with Ph/Pl
  // ---- write P dense bf16 hi/lo into A/B regions ----
  {
    unsigned short* Ph = Qh;
    unsigned short* Pl = Ql;
    const int n0 = wn + l15, n1 = wn + 16 + l15;
    #pragma unroll
    for (int mt=0; mt<8; ++mt){
      #pragma unroll
      for (int r=0; r<4; ++r){
        int m = mt*16 + q*4 + r;
        float v0 = acc3[mt][0][r], v1 = acc3[mt][1][r];
        unsigned short h0 = f2bf(v0), h1 = f2bf(v1);
        Ph[m*136 + n0] = h0; Pl[m*136 + n0] = f2bf(v0 - bf2f(h0));
        Ph[m*136 + n1] = h1; Pl[m*136 + n1] = f2bf(v1 - bf2f(h1));
      }
    }
  }
  __syncthreads();
  // ---- phase PP^T: self cross-product, hi/lo 3-pass MFMA ----
  f32x4 acc2[8][2];
  #pragma unroll
  for (int mt=0; mt<8; ++mt){ acc2[mt][0]=z4; acc2[mt][1]=z4; }
  #pragma unroll
  for (int kc2 = 0; kc2 < 4; ++kc2){
    const int ko = kc2*32 + q*8;
    short8 b0h = *(const short8*)(Qh + (wn      + l15)*136 + ko);
    short8 b1h = *(const short8*)(Qh + (wn + 16 + l15)*136 + ko);
    short8 b0l = *(const short8*)(Ql + (wn      + l15)*136 + ko);
    short8 b1l = *(const short8*)(Ql + (wn + 16 + l15)*136 + ko);
    #pragma unroll
    for (int mt=0; mt<8; ++mt){
      short8 ah = *(const short8*)(Qh + (mt*16 + l15)*136 + ko);
      short8 al = *(const short8*)(Ql + (mt*16 + l15)*136 + ko);
      acc2[mt][0] = __builtin_amdgcn_mfma_f32_16x16x32_bf16(ah, b0h, acc2[mt][0], 0,0,0);
      acc2[mt][0] = __builtin_amdgcn_mfma_f32_16x16x32_bf16(ah, b0l, acc2[mt][0], 0,0,0);
      acc2[mt][0] = __builtin_amdgcn_mfma_f32_16x16x32_bf16(al, b0h, acc2[mt][0], 0,0,0);
      acc2[mt][1] = __builtin_amdgcn_mfma_f32_16x16x32_bf16(ah, b1h, acc2[mt][1], 0,0,0);
      acc2[mt][1] = __builtin_amdgcn_mfma_f32_16x16x32_bf16(ah, b1l, acc2[mt][1], 0,0,0);
      acc2[mt][1] = __builtin_amdgcn_mfma_f32_16x16x32_bf16(al, b1h, acc2[mt][1], 0,0,0);
    }
  }
  // ---- C epilogue: C = Q(regs) - PP^T -> bf16 hi/lo global ----
  #pragma unroll
  for (int nt=0; nt<2; ++nt){
    int n = wn + nt*16 + l15;
    #pragma unroll
    for (int mt=0; mt<8; ++mt){
      #pragma unroll
      for (int r=0; r<4; ++r){
        int m = mt*16 + q*4 + r;
        float c = acc[mt][nt][r] - acc2[mt][nt][r];
        unsigned short hi = f2bf(c);
        unsigned short lo = f2bf(c - bf2f(hi));
        Chi[vbase + m*128 + n] = hi;
        Clo[vbase + m*128 + n] = lo;
      }
    }
  }
}

// ---------------- K9: fused main — B-tile 64 for occupancy ----------------
// grid (64 bblk, 64 ho), 256 thr. Each block: 128 m x 64 b; wave owns 16 b-cols.
// LDS: phase1 zsl[128][40]+xsl[64][40] (15360 B) aliased by kufT[64][136] (17408 B);
// floats at +17408 (1280 B). Total 18688 B -> ~8 blocks/CU.
__global__ __launch_bounds__(256) void k_main(
    const unsigned short* __restrict__ zs, const unsigned short* __restrict__ xs,
    const float* __restrict__ zn2, const float* __restrict__ xn2,
    const float* __restrict__ wg, const unsigned short* __restrict__ Chi,
    const unsigned short* __restrict__ Clo, const float* __restrict__ sf2,
    const int* flagp, void* __restrict__ out){
  const int bblk = blockIdx.x, ho = blockIdx.y, h = ho >> 5;
  const int tid = threadIdx.x;
  const int lane = tid & 63, l15 = lane & 15, q = lane >> 4;
  const int wn16 = (tid >> 6) * 16;
  const int isbf = *flagp;
  extern __shared__ char smem[];
  unsigned short* zsl  = (unsigned short*)smem;     // [128][40] (phase 1)
  unsigned short* xsl  = zsl + 128*40;              // [64][40]  (phase 1)
  unsigned short* kufT = (unsigned short*)smem;     // [64][136] (phase 2, aliases)
  float* zn2l = (float*)(smem + 17408);             // [128]
  float* xn2l = zn2l + 128;                         // [64]
  float* wl   = xn2l + 64;                          // [128]

  if (tid < 128){
    zn2l[tid] = zn2[ho*128 + tid];
    wl[tid]   = wg[ho*128 + tid];
  }
  if (tid < 64) xn2l[tid] = xn2[(size_t)h*B_ + bblk*64 + tid];
  const size_t zbase = (size_t)ho * 32768;
  const size_t xbase = ((size_t)h*B_ + bblk*64) * 256;
  const f32x4 z4 = {0.f,0.f,0.f,0.f};
  f32x4 acc[8];
  #pragma unroll
  for (int mt=0; mt<8; ++mt) acc[mt] = z4;

  // phase 1: cross = zs @ xs^T (K=256, 8 chunks of 32)
  for (int kc = 0; kc < 8; ++kc){
    __syncthreads();
    #pragma unroll
    for (int p0 = 0; p0 < 3; ++p0){
      int p = p0*256 + tid;       // 0..511 z rows, 512..767 x rows
      if (p < 512){
        int row = p >> 2, seg = p & 3;
        uint4 v = *(const uint4*)(zs + zbase + (size_t)row*256 + kc*32 + seg*8);
        *(uint4*)(zsl + row*40 + seg*8) = v;
      } else {
        int pp = p - 512;
        int row = pp >> 2, seg = pp & 3;
        uint4 v = *(const uint4*)(xs + xbase + (size_t)row*256 + kc*32 + seg*8);
        *(uint4*)(xsl + row*40 + seg*8) = v;
      }
    }
    __syncthreads();
    short8 b0 = *(const short8*)(xsl + (wn16 + l15)*40 + q*8);
    #pragma unroll
    for (int mt=0; mt<8; ++mt){
      short8 a = *(const short8*)(zsl + (mt*16 + l15)*40 + q*8);
      acc[mt] = __builtin_amdgcn_mfma_f32_16x16x32_bf16(a, b0, acc[mt], 0,0,0);
    }
  }
  __syncthreads();   // all LDS reads of zsl/xsl done before kufT (alias) is written
  // phase 1 epilogue: kuf = sf2*exp(-0.5*d2); mu partial; store bf16 kufT
  const float s2 = sf2[h];
  float mu0 = 0.f;
  {
    const int bl = wn16 + l15;
    const float xn = xn2l[bl];
    #pragma unroll
    for (int mt=0; mt<8; ++mt){
      const int m0 = mt*16 + q*4;
      float kf[4];
      #pragma unroll
      for (int r=0; r<4; ++r){
        float d2 = fmaxf(zn2l[m0+r] + xn - 2.f*acc[mt][r], 0.f);
        kf[r] = s2 * __expf(-0.5f*d2);
        mu0 += wl[m0+r] * kf[r];
      }
      uint2 pk;
      pk.x = (unsigned)f2bf(kf[0]) | ((unsigned)f2bf(kf[1]) << 16);
      pk.y = (unsigned)f2bf(kf[2]) | ((unsigned)f2bf(kf[3]) << 16);
      *(uint2*)(kufT + bl*136 + m0) = pk;
    }
  }
  __syncthreads();
  // phase 2: T = (Chi + Clo) @ kuf   (K=128, 4 chunks of 32)
  f32x4 acc2[8];
  #pragma unroll
  for (int mt=0; mt<8; ++mt) acc2[mt] = z4;
  const unsigned short* Ch = Chi + (size_t)ho*16384;
  const unsigned short* Cl = Clo + (size_t)ho*16384;
  #pragma unroll
  for (int kc2 = 0; kc2 < 4; ++kc2){
    short8 b0 = *(const short8*)(kufT + (wn16 + l15)*136 + kc2*32 + q*8);
    #pragma unroll
    for (int mt=0; mt<8; ++mt){
      short8 ah = *(const short8*)(Ch + (mt*16 + l15)*128 + kc2*32 + q*8);
      acc2[mt] = __builtin_amdgcn_mfma_f32_16x16x32_bf16(ah, b0, acc2[mt], 0,0,0);
      short8 al = *(const short8*)(Cl + (mt*16 + l15)*128 + kc2*32 + q*8);
      acc2[mt] = __builtin_amdgcn_mfma_f32_16x16x32_bf16(al, b0, acc2[mt], 0,0,0);
    }
  }
  // phase 2 epilogue: s2p = sum_m kuf[m][b] * T[m][b]
  float s2p0 = 0.f;
  {
    const int bl = wn16 + l15;
    #pragma unroll
    for (int mt=0; mt<8; ++mt){
      const int m0 = mt*16 + q*4;
      uint2 pk = *(const uint2*)(kufT + bl*136 + m0);
      f32x4 t = acc2[mt];
      s2p0 += bf2f((unsigned short)(pk.x & 0xffff)) * t[0]
            + bf2f((unsigned short)(pk.x >> 16))    * t[1]
            + bf2f((unsigned short)(pk.y & 0xffff)) * t[2]
            + bf2f((unsigned short)(pk.y >> 16))    * t[3];
    }
  }
  mu0  += __shfl_xor(mu0, 16);  mu0  += __shfl_xor(mu0, 32);
  s2p0 += __shfl_xor(s2p0, 16); s2p0 += __shfl_xor(s2p0, 32);
  if (lane < 16){
    size_t col = (size_t)ho*B_ + bblk*64 + wn16 + lane;
    stout(out, col,                 mu0,       isbf);
    stout(out, (size_t)HO*B_ + col, s2 - s2p0, isbf);
  }
}

// ---------------- launch ----------------
extern "C" void kernel_launch(void* const* d_in, const int* in_sizes, int n_in,
                              void* d_out, int out_size, void* d_ws, size_t ws_size,
                              hipStream_t stream) {
  const void* x      = d_in[0];
  const void* z      = d_in[1];
  const void* u_mean = d_in[2];
  const void* u_tril = d_in[3];
  const void* theta  = d_in[4];
  char* ws = (char*)d_ws;

  int*   flag   = (int*)(ws + OFF_FLAG);
  float* inv_ls = (float*)(ws + OFF_INVLS);
  float* sf2    = (float*)(ws + OFF_SF2);
  float* zn2    = (float*)(ws + OFF_ZN2);
  float* xn2    = (float*)(ws + OFF_XN2);
  float* wv     = (float*)(ws + OFF_W);
  unsigned short* zsw = (unsigned short*)(ws + OFF_ZS);
  unsigned short* xsw = (unsigned short*)(ws + OFF_XS);
  unsigned short* VTh = (unsigned short*)(ws + OFF_VTH);
  unsigned short* VTl = (unsigned short*)(ws + OFF_VTL);
  unsigned short* Chi = (unsigned short*)(ws + OFF_CHI);
  unsigned short* Clo = (unsigned short*)(ws + OFF_CLO);

  k_hypers<<<1, 256, 0, stream>>>(theta, x, flag, inv_ls, sf2);
  k_scale<<<dim3(2048, 2), 256, 0, stream>>>(x, z, flag, inv_ls, xsw, zsw, xn2, zn2);
  k_kufact<<<64, 256, (64*TSZ + 128) * 4, stream>>>(zsw, zn2, sf2, VTh, VTl);
  k_QPC<<<64, 256, 139264 + 512 + 2048, stream>>>(VTh, VTl, u_mean, u_tril, flag, wv, Chi, Clo);
  k_main<<<dim3(64, 64), 256, 18688, stream>>>(zsw, xsw, zn2, xn2, wv, Chi, Clo, sf2, flag, (void*)d_out);
}

// Round 13
// 300.493 us; speedup vs baseline: 1.1186x; 1.1186x over previous
//
#include <hip/hip_runtime.h>
#include <cstdint>
#include <cstddef>

// ---------------- constants ----------------
constexpr int B_   = 4096;
constexpr int DIN  = 256;
constexpr int OUT_ = 32;
constexpr int MM   = 128;
constexpr int NH_  = 2;
constexpr int HO   = 64;          // NH*OUT
constexpr int TRIL = 8256;        // 128*129/2
constexpr float JIT = 1e-4f;

// ---------------- workspace layout ----------------
constexpr size_t al4k(size_t x){ return (x + 4095) & ~size_t(4095); }
constexpr size_t OFF_FLAG  = 0;                               // int
constexpr size_t OFF_INVLS = 4096;                            // f32 [2][256]
constexpr size_t OFF_SF2   = al4k(OFF_INVLS + 2*256*4);       // f32 [2]
constexpr size_t OFF_ZN2   = al4k(OFF_SF2 + 64);              // f32 [2][4096]
constexpr size_t OFF_XN2   = al4k(OFF_ZN2 + 8192*4);          // f32 [2][4096]
constexpr size_t OFF_W     = al4k(OFF_XN2 + 8192*4);          // f32 [64][128]
constexpr size_t OFF_ZS    = al4k(OFF_W + 8192*4);            // bf16 [2][4096][256]
constexpr size_t OFF_XS    = al4k(OFF_ZS + (size_t)2097152*2);
constexpr size_t OFF_VTH   = al4k(OFF_XS + (size_t)2097152*2); // bf16 [64][128][128] V^T hi
constexpr size_t OFF_VTL   = al4k(OFF_VTH + (size_t)1048576*2);// bf16 [64][128][128] V^T lo
constexpr size_t OFF_CHI   = al4k(OFF_VTL + (size_t)1048576*2);// bf16 [64][128][128]
constexpr size_t OFF_CLO   = al4k(OFF_CHI + (size_t)1048576*2);

typedef float f32x4 __attribute__((ext_vector_type(4)));
typedef short short8 __attribute__((ext_vector_type(8)));

__device__ __forceinline__ float bf2f(unsigned short u){
  union{unsigned int i; float f;} v; v.i = ((unsigned)u) << 16; return v.f;
}
__device__ __forceinline__ unsigned short f2bf(float f){
  union{float f; unsigned int i;} v; v.f = f;
  unsigned int r = v.i + 0x7fffu + ((v.i >> 16) & 1u);
  return (unsigned short)(r >> 16);
}
__device__ __forceinline__ float ldin(const void* p, size_t i, int isbf){
  if (isbf) return bf2f(((const unsigned short*)p)[i]);
  return ((const float*)p)[i];
}
__device__ __forceinline__ void stout(void* p, size_t i, float v, int isbf){
  if (isbf) ((unsigned short*)p)[i] = f2bf(v);
  else ((float*)p)[i] = v;
}
// async global->LDS, 16B per lane; LDS dest = wave-uniform base + lane*16
__device__ __forceinline__ void gl_lds16(const unsigned short* g, unsigned short* l){
  __builtin_amdgcn_global_load_lds(
      (const __attribute__((address_space(1))) unsigned int*)g,
      (__attribute__((address_space(3))) unsigned int*)l, 16, 0, 0);
}

// ---------------- K1: detect dtype + hypers (merged) ----------------
__global__ void k_hypers(const void* __restrict__ theta, const void* __restrict__ x,
                         int* __restrict__ flagp,
                         float* __restrict__ inv_ls, float* __restrict__ sf2){
  __shared__ int sflag;
  int t = threadIdx.x;
  if (t < 64){
    unsigned int w0 = ((const unsigned int*)theta)[t];
    unsigned int w1 = ((const unsigned int*)x)[t];
    float a0 = fabsf(bf2f((unsigned short)(w0 & 0xffffu)));
    float a1 = fabsf(bf2f((unsigned short)(w1 & 0xffffu)));
    int c = ((a0 > 9.3e-10f && a0 < 64.f) ? 1 : 0) + ((a1 > 9.3e-10f && a1 < 64.f) ? 1 : 0);
    c += __shfl_down(c, 32); c += __shfl_down(c, 16); c += __shfl_down(c, 8);
    c += __shfl_down(c, 4);  c += __shfl_down(c, 2);  c += __shfl_down(c, 1);
    if (t == 0){ sflag = (c >= 64) ? 1 : 0; *flagp = sflag; }
  }
  __syncthreads();
  const int isbf = sflag;
  for (int i = t; i < NH_*257; i += blockDim.x){
    int h = i / 257, j = i - h*257;
    float v = ldin(theta, i, isbf);
    if (j == 0) sf2[h] = __expf(v);
    else inv_ls[h*DIN + j - 1] = __expf(-v);
  }
}

// ---------------- K2: scale x and z by 1/ls -> bf16 + squared norms (merged) --------
__global__ void k_scale(const void* __restrict__ xsrc, const void* __restrict__ zsrc,
                        const int* flagp, const float* __restrict__ inv_ls,
                        unsigned short* __restrict__ xdst, unsigned short* __restrict__ zdst,
                        float* __restrict__ xn2, float* __restrict__ zn2){
  const int isbf = *flagp;
  const int h = blockIdx.y;
  const int wave = threadIdx.x >> 6, lane = threadIdx.x & 63;
  int bx = blockIdx.x;
  const void* src; unsigned short* dst; float* n2; int r;
  if (bx < 1024){ src = xsrc; dst = xdst; n2 = xn2; r = bx*4 + wave; }
  else          { src = zsrc; dst = zdst; n2 = zn2; r = (bx-1024)*4 + wave; }
  const int d0 = lane*4;
  float v[4];
  if (isbf){
    uint2 uu = *(const uint2*)((const unsigned short*)src + (size_t)r*DIN + d0);
    v[0]=bf2f((unsigned short)(uu.x & 0xffffu)); v[1]=bf2f((unsigned short)(uu.x >> 16));
    v[2]=bf2f((unsigned short)(uu.y & 0xffffu)); v[3]=bf2f((unsigned short)(uu.y >> 16));
  } else {
    f32x4 f = *(const f32x4*)((const float*)src + (size_t)r*DIN + d0);
    v[0]=f[0]; v[1]=f[1]; v[2]=f[2]; v[3]=f[3];
  }
  const float* il = inv_ls + h*DIN + d0;
  unsigned short rb[4];
  float p = 0.f;
  #pragma unroll
  for (int k = 0; k < 4; ++k){
    float s = v[k] * il[k];
    rb[k] = f2bf(s);
    float q = bf2f(rb[k]);
    p += q*q;
  }
  uint2 pk;
  pk.x = (unsigned)rb[0] | ((unsigned)rb[1] << 16);
  pk.y = (unsigned)rb[2] | ((unsigned)rb[3] << 16);
  *(uint2*)(dst + ((size_t)h*4096 + r)*DIN + d0) = pk;
  p += __shfl_xor(p, 32); p += __shfl_xor(p, 16); p += __shfl_xor(p, 8);
  p += __shfl_xor(p, 4);  p += __shfl_xor(p, 2);  p += __shfl_xor(p, 1);
  if (lane == 0) n2[(size_t)h*4096 + r] = p;
}

// ---------------- K3: kuu (MFMA) + blocked Cholesky + trtri, fused per head ---------
constexpr int TLD = 20;          // tile leading dim (floats)
constexpr int TSZ = 16*TLD;      // 320 floats per tile
__device__ __forceinline__ int tb(int bi, int bj){ return (bi*(bi+1)/2 + bj)*TSZ; }
__device__ __forceinline__ int vb(int bi, int bj){ return (36 + bi*(bi-1)/2 + bj)*TSZ; }
__device__ __forceinline__ int tri_bi(int t){
  int bi = (int)((sqrtf(8.f*t + 1.f) - 1.f) * 0.5f);
  while ((bi+1)*(bi+2)/2 <= t) ++bi;
  while (bi*(bi+1)/2 > t) --bi;
  return bi;
}

__global__ __launch_bounds__(256) void k_kufact(
    const unsigned short* __restrict__ zs, const float* __restrict__ zn2,
    const float* __restrict__ sf2,
    unsigned short* __restrict__ VTh, unsigned short* __restrict__ VTl){
  const int ho = blockIdx.x, h = ho >> 5;
  const int tid = threadIdx.x;
  const int lane = tid & 63, wid = tid >> 6;
  const int l15 = lane & 15, q = lane >> 4;
  const int wn = wid * 32;
  extern __shared__ float T[];      // 64 tiles (80 KB); staging zsl aliases T[0..2048)
  unsigned short* zsl = (unsigned short*)T;   // [128][32] swizzled
  float* zn2l = T + 64*TSZ;                   // [128]
  if (tid < 128) zn2l[tid] = zn2[ho*128 + tid];
  const size_t zbase = (size_t)ho * 32768;
  const int sw = ((q ^ ((l15 >> 1) & 3)) << 3);
  const f32x4 z4 = {0.f,0.f,0.f,0.f};
  f32x4 acc[8][2];
  #pragma unroll
  for (int mt=0; mt<8; ++mt){ acc[mt][0]=z4; acc[mt][1]=z4; }
  for (int kc = 0; kc < 8; ++kc){
    __syncthreads();
    {
      int rA = wn + (lane >> 2);
      int sg = ((lane & 3) ^ ((rA >> 1) & 3)) << 3;
      gl_lds16(zs + zbase + (size_t)rA*256 + kc*32 + sg, zsl + wn*32);
      gl_lds16(zs + zbase + (size_t)(rA+16)*256 + kc*32 + sg, zsl + (wn+16)*32);
    }
    __syncthreads();
    short8 b0 = *(const short8*)(zsl + (wn      + l15)*32 + sw);
    short8 b1 = *(const short8*)(zsl + (wn + 16 + l15)*32 + sw);
    #pragma unroll
    for (int mt=0; mt<8; ++mt){
      short8 a = *(const short8*)(zsl + (mt*16 + l15)*32 + sw);
      acc[mt][0] = __builtin_amdgcn_mfma_f32_16x16x32_bf16(a, b0, acc[mt][0], 0,0,0);
      acc[mt][1] = __builtin_amdgcn_mfma_f32_16x16x32_bf16(a, b1, acc[mt][1], 0,0,0);
    }
  }
  __syncthreads();   // all zsl reads done before tiles (alias) are written
  // ---- epilogue: kuu -> T tiles (lower + full diag), + jitter ----
  const float s2v = sf2[h];
  #pragma unroll
  for (int nt=0; nt<2; ++nt){
    int n = wn + nt*16 + l15;
    float nn = zn2l[n];
    int bn = n >> 4;
    #pragma unroll
    for (int mt=0; mt<8; ++mt){
      #pragma unroll
      for (int r=0; r<4; ++r){
        int m = mt*16 + q*4 + r;
        float d2 = fmaxf(zn2l[m] + nn - 2.f*acc[mt][nt][r], 0.f);
        float a = s2v * __expf(-0.5f*d2);
        if (m == n) a += JIT;
        int bm = m >> 4;
        if (bn <= bm) T[tb(bm, bn) + (m & 15)*TLD + (n & 15)] = a;
      }
    }
  }
  __syncthreads();
  // ---- blocked Cholesky, panel width 16 ----
  for (int kb = 0; kb < 8; ++kb){
    if (wid == 0){
      float* D = T + tb(kb, kb);
      const int r = lane & 15;
      const bool act = (lane < 16);
      float a[16];
      #pragma unroll
      for (int k = 0; k < 16; ++k) a[k] = 0.f;
      if (act){
        #pragma unroll
        for (int k2 = 0; k2 < 4; ++k2)
          *(f32x4*)(a + 4*k2) = *(const f32x4*)(D + r*TLD + 4*k2);
      }
      #pragma unroll
      for (int c = 0; c < 16; ++c){
        float pr[16];
        #pragma unroll
        for (int k = 0; k < 16; ++k) pr[k] = __shfl(a[k], c);
        float rsq = rsqrtf(pr[c]);
        if (act && r >= c) a[c] *= rsq;
        float lrc = a[c];
        #pragma unroll
        for (int k = 0; k < 16; ++k)
          if (k > c && act && r > c) a[k] -= lrc * (pr[k] * rsq);
      }
      float v[16];
      #pragma unroll
      for (int k = 0; k < 16; ++k) v[k] = 0.f;
      const int c = lane & 15;
      #pragma unroll
      for (int i = 0; i < 16; ++i){
        float lrow[16];
        #pragma unroll
        for (int k = 0; k < 16; ++k) lrow[k] = __shfl(a[k], i);
        float rli = 1.f / lrow[i];
        float s = 0.f;
        #pragma unroll
        for (int k = 0; k < 16; ++k)
          if (k < i) s += ((k >= c) ? lrow[k]*v[k] : 0.f);
        v[i] = (c == i) ? rli : ((c < i) ? -s*rli : 0.f);
      }
      if (act){
        #pragma unroll
        for (int i = 0; i < 16; ++i) D[i*TLD + c] = v[i];
      }
    }
    __syncthreads();
    {
      const int gi = kb*16 + 16 + tid;
      if (gi < 128){
        float* Bp = T + tb(gi >> 4, kb) + (gi & 15)*TLD;
        const float* Vd = T + tb(kb, kb);
        float b[16], nb[16];
        #pragma unroll
        for (int k2 = 0; k2 < 4; ++k2) *(f32x4*)(b + 4*k2) = *(const f32x4*)(Bp + 4*k2);
        #pragma unroll
        for (int j = 0; j < 16; ++j){
          float s = 0.f;
          #pragma unroll
          for (int k = 0; k < 16; ++k)
            if (k <= j) s += b[k] * Vd[j*TLD + k];
          nb[j] = s;
        }
        #pragma unroll
        for (int k2 = 0; k2 < 4; ++k2) *(f32x4*)(Bp + 4*k2) = *(const f32x4*)(nb + 4*k2);
      }
    }
    __syncthreads();
    {
      const int D8 = 7 - kb;
      const int Tn = D8*(D8+1)/2;
      const int r15 = lane & 15, cg = lane >> 4, c0 = cg*4;
      for (int tt = wid; tt < Tn; tt += 4){
        int bi1 = tri_bi(tt);
        int bj1 = tt - bi1*(bi1+1)/2;
        int bi = kb + 1 + bi1, bj = kb + 1 + bj1;
        const float* Lr = T + tb(bi, kb) + r15*TLD;
        const float* Lc = T + tb(bj, kb) + c0*TLD;
        float* Cp = T + tb(bi, bj) + r15*TLD + c0;
        float lr[16];
        #pragma unroll
        for (int k2 = 0; k2 < 4; ++k2) *(f32x4*)(lr + 4*k2) = *(const f32x4*)(Lr + 4*k2);
        f32x4 accv = *(const f32x4*)Cp;
        #pragma unroll
        for (int cc = 0; cc < 4; ++cc){
          float lc[16];
          #pragma unroll
          for (int k2 = 0; k2 < 4; ++k2) *(f32x4*)(lc + 4*k2) = *(const f32x4*)(Lc + cc*TLD + 4*k2);
          float s = 0.f;
          #pragma unroll
          for (int k = 0; k < 16; ++k) s += lr[k]*lc[k];
          accv[cc] -= s;
        }
        *(f32x4*)Cp = accv;
      }
    }
    __syncthreads();
  }
  // ---- trtri by anti-diagonal wavefronts ----
  {
    const int r15 = lane & 15, c0 = (lane >> 4)*4;
    for (int d = 1; d < 8; ++d){
      for (int tt = wid; tt < 8 - d; tt += 4){
        const int bi = d + tt, jb = bi - d;
        float W0=0.f, W1=0.f, W2=0.f, W3=0.f;
        for (int k = jb; k < bi; ++k){
          const float* Lt = T + tb(bi, k) + r15*TLD;
          const float* Vt = (k == jb) ? (T + tb(jb, jb)) : (T + vb(k, jb));
          float lr[16];
          #pragma unroll
          for (int k2 = 0; k2 < 4; ++k2) *(f32x4*)(lr + 4*k2) = *(const f32x4*)(Lt + 4*k2);
          #pragma unroll
          for (int kk = 0; kk < 16; ++kk){
            f32x4 vv = *(const f32x4*)(Vt + kk*TLD + c0);
            W0 += lr[kk]*vv[0]; W1 += lr[kk]*vv[1];
            W2 += lr[kk]*vv[2]; W3 += lr[kk]*vv[3];
          }
        }
        const float* Vd = T + tb(bi, bi) + r15*TLD;
        const int cgl = (lane >> 4);
        f32x4 Rr = {0.f,0.f,0.f,0.f};
        #pragma unroll
        for (int k = 0; k < 16; ++k){
          float vd = Vd[k];
          float w0 = __shfl(W0, (cgl<<4)|k);
          float w1 = __shfl(W1, (cgl<<4)|k);
          float w2 = __shfl(W2, (cgl<<4)|k);
          float w3 = __shfl(W3, (cgl<<4)|k);
          Rr[0] -= vd*w0; Rr[1] -= vd*w1; Rr[2] -= vd*w2; Rr[3] -= vd*w3;
        }
        *(f32x4*)(T + vb(bi, jb) + r15*TLD + c0) = Rr;
      }
      __syncthreads();
    }
  }
  // ---- epilogue: VT dense bf16 hi/lo (VT[c][r] = V[r][c]) ----
  const size_t obase = (size_t)ho * 16384;
  for (int e = tid; e < 16384; e += 256){
    int c = e >> 7, rr = e & 127;
    int bc = c >> 4, br = rr >> 4;
    float v = 0.f;
    if (br == bc)      v = T[tb(br, bc) + (rr & 15)*TLD + (c & 15)];
    else if (br > bc)  v = T[vb(br, bc) + (rr & 15)*TLD + (c & 15)];
    unsigned short hi = f2bf(v);
    unsigned short lo = f2bf(v - bf2f(hi));
    VTh[obase + e] = hi;
    VTl[obase + e] = lo;
  }
}

// ---------------- K4: fused Q = V^T V + w + P = Q S + C = Q - P P^T (all MFMA) ------
__global__ __launch_bounds__(256) void k_QPC(
    const unsigned short* __restrict__ VTh, const unsigned short* __restrict__ VTl,
    const void* __restrict__ u_mean, const void* __restrict__ u_tril, const int* flagp,
    float* __restrict__ wg, unsigned short* __restrict__ Chi,
    unsigned short* __restrict__ Clo){
  const int ho = blockIdx.x, o = ho & 31;
  const int tid = threadIdx.x;
  const int lane = tid & 63, l15 = lane & 15, q = lane >> 4;
  const int wn = (tid >> 6) * 32;
  const int wave = tid >> 6;
  const int isbf = *flagp;
  extern __shared__ char smem[];
  unsigned short* Qh  = (unsigned short*)smem;              // [128][136], aliases staging
  unsigned short* Ql  = (unsigned short*)(smem + 34816);    // [128][136]
  unsigned short* Sth = (unsigned short*)(smem + 69632);    // [128][136]
  unsigned short* Stl = (unsigned short*)(smem + 104448);   // [128][136]
  float* ul    = (float*)(smem + 139264);                   // [128]
  float* wpart = ul + 128;                                  // [4][128]
  unsigned short* hsl = Qh;             // staging alias [128][32]
  unsigned short* lsl = Qh + 4096;
  if (tid < 128) ul[tid] = ldin(u_mean, (size_t)o*128 + tid, isbf);
  // ---- fill St = S^T: consecutive threads vary j -> coalesced global reads ----
  // St[j][k] = S[k][j]; global addr k(k+1)/2 + j contiguous in j.
  for (int e = tid; e < 16384; e += 256){
    int k = e >> 7, j = e & 127;
    float val = 0.f;
    if (j <= k) val = ldin(u_tril, (size_t)o*TRIL + (size_t)k*(k+1)/2 + j, isbf);
    unsigned short hi = f2bf(val);
    Sth[j*136 + k] = hi;
    Stl[j*136 + k] = f2bf(val - bf2f(hi));
  }
  const size_t vbase = (size_t)ho * 16384;
  const int sw = ((q ^ ((l15 >> 1) & 3)) << 3);
  const f32x4 z4 = {0.f,0.f,0.f,0.f};
  // ---- phase Q: Q = VT * VT^T via hi/lo 3-pass MFMA ----
  f32x4 acc[8][2];
  #pragma unroll
  for (int mt=0; mt<8; ++mt){ acc[mt][0]=z4; acc[mt][1]=z4; }
  for (int kc = 0; kc < 4; ++kc){
    __syncthreads();
    {
      int rA = wn + (lane >> 2);
      int sg = ((lane & 3) ^ ((rA >> 1) & 3)) << 3;
      gl_lds16(VTh + vbase + (size_t)rA*128 + kc*32 + sg, hsl + wn*32);
      gl_lds16(VTl + vbase + (size_t)rA*128 + kc*32 + sg, lsl + wn*32);
      gl_lds16(VTh + vbase + (size_t)(rA+16)*128 + kc*32 + sg, hsl + (wn+16)*32);
      gl_lds16(VTl + vbase + (size_t)(rA+16)*128 + kc*32 + sg, lsl + (wn+16)*32);
    }
    __syncthreads();
    short8 b0h = *(const short8*)(hsl + (wn      + l15)*32 + sw);
    short8 b1h = *(const short8*)(hsl + (wn + 16 + l15)*32 + sw);
    short8 b0l = *(const short8*)(lsl + (wn      + l15)*32 + sw);
    short8 b1l = *(const short8*)(lsl + (wn + 16 + l15)*32 + sw);
    #pragma unroll
    for (int mt=0; mt<8; ++mt){
      short8 ah = *(const short8*)(hsl + (mt*16 + l15)*32 + sw);
      short8 al = *(const short8*)(lsl + (mt*16 + l15)*32 + sw);
      acc[mt][0] = __builtin_amdgcn_mfma_f32_16x16x32_bf16(ah, b0h, acc[mt][0], 0,0,0);
      acc[mt][0] = __builtin_amdgcn_mfma_f32_16x16x32_bf16(ah, b0l, acc[mt][0], 0,0,0);
      acc[mt][0] = __builtin_amdgcn_mfma_f32_16x16x32_bf16(al, b0h, acc[mt][0], 0,0,0);
      acc[mt][1] = __builtin_amdgcn_mfma_f32_16x16x32_bf16(ah, b1h, acc[mt][1], 0,0,0);
      acc[mt][1] = __builtin_amdgcn_mfma_f32_16x16x32_bf16(ah, b1l, acc[mt][1], 0,0,0);
      acc[mt][1] = __builtin_amdgcn_mfma_f32_16x16x32_bf16(al, b1h, acc[mt][1], 0,0,0);
    }
  }
  // ---- w = Q u (shuffle reduce) ----
  {
    float u0 = ul[wn + l15], u1 = ul[wn + 16 + l15];
    float wpm[32];
    #pragma unroll
    for (int mt=0; mt<8; ++mt){
      #pragma unroll
      for (int r=0; r<4; ++r)
        wpm[mt*4+r] = acc[mt][0][r]*u0 + acc[mt][1][r]*u1;
    }
    #pragma unroll
    for (int i = 0; i < 32; ++i){
      wpm[i] += __shfl_xor(wpm[i], 1);
      wpm[i] += __shfl_xor(wpm[i], 2);
      wpm[i] += __shfl_xor(wpm[i], 4);
      wpm[i] += __shfl_xor(wpm[i], 8);
    }
    if (l15 == 0){
      #pragma unroll
      for (int i = 0; i < 32; ++i){
        int m = (i>>2)*16 + q*4 + (i&3);
        wpart[wave*128 + m] = wpm[i];
      }
    }
  }
  __syncthreads();   // staging reads done (safe to overwrite Qh region) + wpart visible
  if (tid < 128)
    wg[ho*128 + tid] = wpart[tid] + wpart[128+tid] + wpart[256+tid] + wpart[384+tid];
  // ---- write Q dense bf16 hi/lo to LDS ----
  {
    const int n0 = wn + l15, n1 = wn + 16 + l15;
    #pragma unroll
    for (int mt=0; mt<8; ++mt){
      #pragma unroll
      for (int r=0; r<4; ++r){
        int m = mt*16 + q*4 + r;
        float v0 = acc[mt][0][r], v1 = acc[mt][1][r];
        unsigned short h0 = f2bf(v0), h1 = f2bf(v1);
        Qh[m*136 + n0] = h0; Ql[m*136 + n0] = f2bf(v0 - bf2f(h0));
        Qh[m*136 + n1] = h1; Ql[m*136 + n1] = f2bf(v1 - bf2f(h1));
      }
    }
  }
  __syncthreads();   // Qh/Ql + Sth/Stl visible
  // ---- phase P: P = Q*S via MFMA, 3 passes ----
  f32x4 acc3[8][2];
  #pragma unroll
  for (int mt=0; mt<8; ++mt){ acc3[mt][0]=z4; acc3[mt][1]=z4; }
  #pragma unroll
  for (int kc2 = 0; kc2 < 4; ++kc2){
    const int ko = kc2*32 + q*8;
    short8 b0h = *(const short8*)(Sth + (wn      + l15)*136 + ko);
    short8 b1h = *(const short8*)(Sth + (wn + 16 + l15)*136 + ko);
    short8 b0l = *(const short8*)(Stl + (wn      + l15)*136 + ko);
    short8 b1l = *(const short8*)(Stl + (wn + 16 + l15)*136 + ko);
    #pragma unroll
    for (int mt=0; mt<8; ++mt){
      short8 ah = *(const short8*)(Qh + (mt*16 + l15)*136 + ko);
      short8 al = *(const short8*)(Ql + (mt*16 + l15)*136 + ko);
      acc3[mt][0] = __builtin_amdgcn_mfma_f32_16x16x32_bf16(ah, b0h, acc3[mt][0], 0,0,0);
      acc3[mt][0] = __builtin_amdgcn_mfma_f32_16x16x32_bf16(al, b0h, acc3[mt][0], 0,0,0);
      acc3[mt][0] = __builtin_amdgcn_mfma_f32_16x16x32_bf16(ah, b0l, acc3[mt][0], 0,0,0);
      acc3[mt][1] = __builtin_amdgcn_mfma_f32_16x16x32_bf16(ah, b1h, acc3[mt][1], 0,0,0);
      acc3[mt][1] = __builtin_amdgcn_mfma_f32_16x16x32_bf16(al, b1h, acc3[mt][1], 0,0,0);
      acc3[mt][1] = __builtin_amdgcn_mfma_f32_16x16x32_bf16(ah, b1l, acc3[mt][1], 0,0,0);
    }
  }
  __syncthreads();   // all Qh/Ql reads done before overwrite with Ph/Pl
  // ---- write P dense bf16 hi/lo into A/B regions ----
  {
    unsigned short* Ph = Qh;
    unsigned short* Pl = Ql;
    const int n0 = wn + l15, n1 = wn + 16 + l15;
    #pragma unroll
    for (int mt=0; mt<8; ++mt){
      #pragma unroll
      for (int r=0; r<4; ++r){
        int m = mt*16 + q*4 + r;
        float v0 = acc3[mt][0][r], v1 = acc3[mt][1][r];
        unsigned short h0 = f2bf(v0), h1 = f2bf(v1);
        Ph[m*136 + n0] = h0; Pl[m*136 + n0] = f2bf(v0 - bf2f(h0));
        Ph[m*136 + n1] = h1; Pl[m*136 + n1] = f2bf(v1 - bf2f(h1));
      }
    }
  }
  __syncthreads();
  // ---- phase PP^T: self cross-product, hi/lo 3-pass MFMA ----
  f32x4 acc2[8][2];
  #pragma unroll
  for (int mt=0; mt<8; ++mt){ acc2[mt][0]=z4; acc2[mt][1]=z4; }
  #pragma unroll
  for (int kc2 = 0; kc2 < 4; ++kc2){
    const int ko = kc2*32 + q*8;
    short8 b0h = *(const short8*)(Qh + (wn      + l15)*136 + ko);
    short8 b1h = *(const short8*)(Qh + (wn + 16 + l15)*136 + ko);
    short8 b0l = *(const short8*)(Ql + (wn      + l15)*136 + ko);
    short8 b1l = *(const short8*)(Ql + (wn + 16 + l15)*136 + ko);
    #pragma unroll
    for (int mt=0; mt<8; ++mt){
      short8 ah = *(const short8*)(Qh + (mt*16 + l15)*136 + ko);
      short8 al = *(const short8*)(Ql + (mt*16 + l15)*136 + ko);
      acc2[mt][0] = __builtin_amdgcn_mfma_f32_16x16x32_bf16(ah, b0h, acc2[mt][0], 0,0,0);
      acc2[mt][0] = __builtin_amdgcn_mfma_f32_16x16x32_bf16(ah, b0l, acc2[mt][0], 0,0,0);
      acc2[mt][0] = __builtin_amdgcn_mfma_f32_16x16x32_bf16(al, b0h, acc2[mt][0], 0,0,0);
      acc2[mt][1] = __builtin_amdgcn_mfma_f32_16x16x32_bf16(ah, b1h, acc2[mt][1], 0,0,0);
      acc2[mt][1] = __builtin_amdgcn_mfma_f32_16x16x32_bf16(ah, b1l, acc2[mt][1], 0,0,0);
      acc2[mt][1] = __builtin_amdgcn_mfma_f32_16x16x32_bf16(al, b1h, acc2[mt][1], 0,0,0);
    }
  }
  // ---- C epilogue: C = Q(regs) - PP^T -> bf16 hi/lo global ----
  #pragma unroll
  for (int nt=0; nt<2; ++nt){
    int n = wn + nt*16 + l15;
    #pragma unroll
    for (int mt=0; mt<8; ++mt){
      #pragma unroll
      for (int r=0; r<4; ++r){
        int m = mt*16 + q*4 + r;
        float c = acc[mt][nt][r] - acc2[mt][nt][r];
        unsigned short hi = f2bf(c);
        unsigned short lo = f2bf(c - bf2f(hi));
        Chi[vbase + m*128 + n] = hi;
        Clo[vbase + m*128 + n] = lo;
      }
    }
  }
}

// ---------------- K9: fused main — kuf + mu + quadratic-form var (112 µs variant) ---
// LDS union: phase1 zsl/xsl (20480 B) aliased by phase2 kufT (34816 B); floats after.
__global__ __launch_bounds__(256) void k_main(
    const unsigned short* __restrict__ zs, const unsigned short* __restrict__ xs,
    const float* __restrict__ zn2, const float* __restrict__ xn2,
    const float* __restrict__ wg, const unsigned short* __restrict__ Chi,
    const unsigned short* __restrict__ Clo, const float* __restrict__ sf2,
    const int* flagp, void* __restrict__ out){
  const int bblk = blockIdx.x, ho = blockIdx.y, h = ho >> 5;
  const int tid = threadIdx.x;
  const int lane = tid & 63, l15 = lane & 15, q = lane >> 4;
  const int wn = (tid >> 6) * 32;
  const int isbf = *flagp;
  extern __shared__ char smem[];
  unsigned short* zsl  = (unsigned short*)smem;     // [128][40] (phase 1)
  unsigned short* xsl  = zsl + 128*40;              // [128][40] (phase 1)
  unsigned short* kufT = (unsigned short*)smem;     // [128][136] (phase 2, aliases)
  float* zn2l = (float*)(smem + 34816);
  float* xn2l = zn2l + 128;
  float* wl   = xn2l + 128;

  if (tid < 128){
    zn2l[tid] = zn2[ho*128 + tid];
    xn2l[tid] = xn2[(size_t)h*B_ + bblk*128 + tid];
    wl[tid]   = wg[ho*128 + tid];
  }
  const size_t zbase = (size_t)ho * 32768;
  const size_t xbase = ((size_t)h*B_ + bblk*128) * 256;
  const f32x4 z4 = {0.f,0.f,0.f,0.f};
  f32x4 acc[8][2];
  #pragma unroll
  for (int mt=0; mt<8; ++mt){ acc[mt][0]=z4; acc[mt][1]=z4; }

  // phase 1: cross = zs @ xs^T (K=256, 8 chunks of 32)
  for (int kc = 0; kc < 8; ++kc){
    __syncthreads();
    #pragma unroll
    for (int p0 = 0; p0 < 4; ++p0){
      int p = p0*256 + tid;
      int half = p >> 9, pp = p & 511;
      int row = pp >> 2, seg = pp & 3;
      const unsigned short* gsrc = half ? (xs + xbase) : (zs + zbase);
      unsigned short* ldst = half ? xsl : zsl;
      uint4 v = *(const uint4*)(gsrc + row*256 + kc*32 + seg*8);
      *(uint4*)(ldst + row*40 + seg*8) = v;
    }
    __syncthreads();
    short8 b0 = *(const short8*)(xsl + (wn      + l15)*40 + q*8);
    short8 b1 = *(const short8*)(xsl + (wn + 16 + l15)*40 + q*8);
    #pragma unroll
    for (int mt=0; mt<8; ++mt){
      short8 a = *(const short8*)(zsl + (mt*16 + l15)*40 + q*8);
      acc[mt][0] = __builtin_amdgcn_mfma_f32_16x16x32_bf16(a, b0, acc[mt][0], 0,0,0);
      acc[mt][1] = __builtin_amdgcn_mfma_f32_16x16x32_bf16(a, b1, acc[mt][1], 0,0,0);
    }
  }
  __syncthreads();   // all LDS reads of zsl/xsl done before kufT (alias) is written
  // phase 1 epilogue: kuf = sf2*exp(-0.5*d2); mu partial; store bf16 kufT
  const float s2 = sf2[h];
  float mu0 = 0.f, mu1 = 0.f;
  #pragma unroll
  for (int nt=0; nt<2; ++nt){
    const int bl = wn + nt*16 + l15;
    const float xn = xn2l[bl];
    #pragma unroll
    for (int mt=0; mt<8; ++mt){
      const int m0 = mt*16 + q*4;
      float kf[4];
      #pragma unroll
      for (int r=0; r<4; ++r){
        float d2 = fmaxf(zn2l[m0+r] + xn - 2.f*acc[mt][nt][r], 0.f);
        kf[r] = s2 * __expf(-0.5f*d2);
        float wv = wl[m0+r] * kf[r];
        if (nt == 0) mu0 += wv; else mu1 += wv;
      }
      uint2 pk;
      pk.x = (unsigned)f2bf(kf[0]) | ((unsigned)f2bf(kf[1]) << 16);
      pk.y = (unsigned)f2bf(kf[2]) | ((unsigned)f2bf(kf[3]) << 16);
      *(uint2*)(kufT + bl*136 + m0) = pk;
    }
  }
  __syncthreads();
  // phase 2: T = (Chi + Clo) @ kuf   (K=128, 4 chunks of 32)
  f32x4 acc2[8][2];
  #pragma unroll
  for (int mt=0; mt<8; ++mt){ acc2[mt][0]=z4; acc2[mt][1]=z4; }
  const unsigned short* Ch = Chi + (size_t)ho*16384;
  const unsigned short* Cl = Clo + (size_t)ho*16384;
  #pragma unroll
  for (int kc2 = 0; kc2 < 4; ++kc2){
    short8 b0 = *(const short8*)(kufT + (wn      + l15)*136 + kc2*32 + q*8);
    short8 b1 = *(const short8*)(kufT + (wn + 16 + l15)*136 + kc2*32 + q*8);
    #pragma unroll
    for (int mt=0; mt<8; ++mt){
      short8 ah = *(const short8*)(Ch + (mt*16 + l15)*128 + kc2*32 + q*8);
      acc2[mt][0] = __builtin_amdgcn_mfma_f32_16x16x32_bf16(ah, b0, acc2[mt][0], 0,0,0);
      acc2[mt][1] = __builtin_amdgcn_mfma_f32_16x16x32_bf16(ah, b1, acc2[mt][1], 0,0,0);
      short8 al = *(const short8*)(Cl + (mt*16 + l15)*128 + kc2*32 + q*8);
      acc2[mt][0] = __builtin_amdgcn_mfma_f32_16x16x32_bf16(al, b0, acc2[mt][0], 0,0,0);
      acc2[mt][1] = __builtin_amdgcn_mfma_f32_16x16x32_bf16(al, b1, acc2[mt][1], 0,0,0);
    }
  }
  // phase 2 epilogue: s2p = sum_m kuf[m][b] * T[m][b]
  float s2p0 = 0.f, s2p1 = 0.f;
  #pragma unroll
  for (int nt=0; nt<2; ++nt){
    const int bl = wn + nt*16 + l15;
    #pragma unroll
    for (int mt=0; mt<8; ++mt){
      const int m0 = mt*16 + q*4;
      uint2 pk = *(const uint2*)(kufT + bl*136 + m0);
      f32x4 t = acc2[mt][nt];
      float s = bf2f((unsigned short)(pk.x & 0xffff)) * t[0]
              + bf2f((unsigned short)(pk.x >> 16))    * t[1]
              + bf2f((unsigned short)(pk.y & 0xffff)) * t[2]
              + bf2f((unsigned short)(pk.y >> 16))    * t[3];
      if (nt == 0) s2p0 += s; else s2p1 += s;
    }
  }
  mu0  += __shfl_xor(mu0, 16);  mu0  += __shfl_xor(mu0, 32);
  mu1  += __shfl_xor(mu1, 16);  mu1  += __shfl_xor(mu1, 32);
  s2p0 += __shfl_xor(s2p0, 16); s2p0 += __shfl_xor(s2p0, 32);
  s2p1 += __shfl_xor(s2p1, 16); s2p1 += __shfl_xor(s2p1, 32);
  if (lane < 16){
    size_t col = (size_t)ho*B_ + bblk*128 + wn + lane;
    stout(out, col,                        mu0,       isbf);
    stout(out, (size_t)HO*B_ + col,        s2 - s2p0, isbf);
    stout(out, col + 16,                   mu1,       isbf);
    stout(out, (size_t)HO*B_ + col + 16,   s2 - s2p1, isbf);
  }
}

// ---------------- launch ----------------
extern "C" void kernel_launch(void* const* d_in, const int* in_sizes, int n_in,
                              void* d_out, int out_size, void* d_ws, size_t ws_size,
                              hipStream_t stream) {
  const void* x      = d_in[0];
  const void* z      = d_in[1];
  const void* u_mean = d_in[2];
  const void* u_tril = d_in[3];
  const void* theta  = d_in[4];
  char* ws = (char*)d_ws;

  int*   flag   = (int*)(ws + OFF_FLAG);
  float* inv_ls = (float*)(ws + OFF_INVLS);
  float* sf2    = (float*)(ws + OFF_SF2);
  float* zn2    = (float*)(ws + OFF_ZN2);
  float* xn2    = (float*)(ws + OFF_XN2);
  float* wv     = (float*)(ws + OFF_W);
  unsigned short* zsw = (unsigned short*)(ws + OFF_ZS);
  unsigned short* xsw = (unsigned short*)(ws + OFF_XS);
  unsigned short* VTh = (unsigned short*)(ws + OFF_VTH);
  unsigned short* VTl = (unsigned short*)(ws + OFF_VTL);
  unsigned short* Chi = (unsigned short*)(ws + OFF_CHI);
  unsigned short* Clo = (unsigned short*)(ws + OFF_CLO);

  k_hypers<<<1, 256, 0, stream>>>(theta, x, flag, inv_ls, sf2);
  k_scale<<<dim3(2048, 2), 256, 0, stream>>>(x, z, flag, inv_ls, xsw, zsw, xn2, zn2);
  k_kufact<<<64, 256, (64*TSZ + 128) * 4, stream>>>(zsw, zn2, sf2, VTh, VTl);
  k_QPC<<<64, 256, 139264 + 512 + 2048, stream>>>(VTh, VTl, u_mean, u_tril, flag, wv, Chi, Clo);
  k_main<<<dim3(32, 64), 256, 36352, stream>>>(zsw, xsw, zn2, xn2, wv, Chi, Clo, sf2, flag, (void*)d_out);
}